// Round 6
// baseline (145.637 us; speedup 1.0000x reference)
//
#include <hip/hip_runtime.h>
#include <stdint.h>
#include <math.h>

#define HID 64
#define PI_F 3.14159262358979330f

// ---------- fused prep: quaternion table + tail histogram ----------
__global__ void prep(const float* __restrict__ rel, float4* __restrict__ quat, int nrel,
                     const int* __restrict__ eidx, int E, int* __restrict__ hist,
                     int qblocks) {
    if ((int)blockIdx.x < qblocks) {
        int i = blockIdx.x * blockDim.x + threadIdx.x;
        if (i >= nrel * HID) return;
        int r = i >> 6, j = i & 63;
        const float* base = rel + (size_t)r * 4 * HID;
        float rx = base[j];
        float ry = base[HID + j];
        float rz = base[2 * HID + j];
        float th = base[3 * HID + j];
        float theta = th * PI_F;
        float sn = sinf(theta);
        float w  = cosf(theta);
        float tx = sn * rx, ty = sn * ry, tz = sn * rz;
        float norm = sqrtf(tx * tx + ty * ty + tz * tz);
        float inv = 1.0f / fmaxf(norm, 1e-12f);
        float s = sqrtf(fmaxf(1.0f - w * w, 0.0f));
        quat[i] = make_float4(w, s * tx * inv, s * ty * inv, s * tz * inv);
    } else {
        int e = (blockIdx.x - qblocks) * blockDim.x + threadIdx.x;
        if (e >= E) return;
        atomicAdd(hist + eidx[2 * E + e], 1);
    }
}

// ---------- parallel exclusive scan of hist -> base (2 dispatches) ----------
__global__ void scan1(const int* __restrict__ hist, int* __restrict__ base,
                      int* __restrict__ partial, int n) {
    __shared__ int buf[256];
    int tid = threadIdx.x;
    int gid = blockIdx.x * 256 + tid;
    int v = (gid < n) ? hist[gid] : 0;
    buf[tid] = v;
    __syncthreads();
    #pragma unroll
    for (int off = 1; off < 256; off <<= 1) {
        int x = (tid >= off) ? buf[tid - off] : 0;
        __syncthreads();
        buf[tid] += x;
        __syncthreads();
    }
    if (gid < n) base[gid] = buf[tid] - v;        // exclusive within block
    if (tid == 255) partial[blockIdx.x] = buf[255];
}

// Every block redundantly scans the <=256 partials in LDS, applies its offset.
// Writes base (final) and base2 (scatter cursor copy).
__global__ void scan23(int* __restrict__ base, int* __restrict__ base2,
                       const int* __restrict__ partial,
                       int nb, int n, int E) {
    __shared__ int buf[256];
    int tid = threadIdx.x;
    int v = (tid < nb) ? partial[tid] : 0;
    buf[tid] = v;
    __syncthreads();
    #pragma unroll
    for (int off = 1; off < 256; off <<= 1) {
        int x = (tid >= off) ? buf[tid - off] : 0;
        __syncthreads();
        buf[tid] += x;
        __syncthreads();
    }
    int bsum = ((int)blockIdx.x < nb) ? partial[blockIdx.x] : 0;
    int boff = buf[blockIdx.x] - bsum;            // exclusive prefix of this block
    int gid = blockIdx.x * 256 + tid;
    if (gid < n) {
        int bv = base[gid] + boff;
        base[gid] = bv;
        base2[gid] = bv;
    } else if (gid == n) {
        base[n] = E;                              // sentinel
    }
}

// ---------- scatter packed (head, rel) into tail-sorted position ----------
__global__ void scatter_hr(const int* __restrict__ eidx, int E,
                           int* __restrict__ base2,
                           int2* __restrict__ hr) {
    int e = blockIdx.x * blockDim.x + threadIdx.x;
    if (e >= E) return;
    int t = eidx[2 * E + e];
    int pos = atomicAdd(base2 + t, 1);
    hr[pos] = make_int2(eidx[e], eidx[E + e]);
}

// ---------- fused per-tail pass: 16 lanes/edge, 4 edges/wave, 2-deep pipeline ----------
__global__ void seg_reduce(const float* __restrict__ ent,
                           const float4* __restrict__ quat,
                           const int2* __restrict__ hr,
                           const int* __restrict__ base,
                           int n_ent,
                           float* __restrict__ out) {
    int t = blockIdx.x * (blockDim.x >> 6) + (threadIdx.x >> 6);
    int lane = threadIdx.x & 63;
    if (t >= n_ent) return;
    int sub = lane >> 4;                  // edge slot 0..3
    int j   = lane & 15;                  // dim group: dims 4j..4j+3

    int start = base[t];
    int end   = base[t + 1];

    float4* o4 = (float4*)(out + (size_t)t * (4 * HID));
    if (start == end) {                   // empty segment -> zeros
        o4[lane] = make_float4(0.f, 0.f, 0.f, 0.f);
        return;
    }
    int last = end - 1;

    const float4* krow = (const float4*)(ent + (size_t)t * (3 * HID));
    float4 kx = krow[j], ky = krow[16 + j], kz = krow[32 + j];

    float m = -1e30f, dnm = 0.0f;
    float4 ax = make_float4(0.f, 0.f, 0.f, 0.f);
    float4 ay = ax, az = ax, aw = ax;

    // ---- prologue: hr for iter0/iter1; gathers for iter0 (A set) ----
    int2 herA = hr[min(start + sub, last)];
    int2 herB = hr[min(start + 4 + sub, last)];
    const float4* hA = (const float4*)(ent + (size_t)herA.x * (3 * HID));
    float4 hxA = hA[j], hyA = hA[16 + j], hzA = hA[32 + j];
    const float4* qrA = quat + (size_t)herA.y * HID + 4 * j;
    float4 q0A = qrA[0], q1A = qrA[1], q2A = qrA[2], q3A = qrA[3];

    #define COMPUTE(HX, HY, HZ, Q0, Q1, Q2, Q3, K0) { \
        float4 qx, qy, qz, qw; \
        float p = 0.0f; \
        { float ex = HX.x, ey = HY.x, ez = HZ.x; \
          float w = Q0.x, ux = Q0.y, uy = Q0.z, uz = Q0.w; \
          qx.x = w * ex + uy * ez - uz * ey; \
          qy.x = w * ey + uz * ex - ux * ez; \
          qz.x = w * ez + ux * ey - uy * ex; \
          qw.x = -(ux * ex + uy * ey + uz * ez); \
          p += kx.x * qx.x + ky.x * qy.x + kz.x * qz.x; } \
        { float ex = HX.y, ey = HY.y, ez = HZ.y; \
          float w = Q1.x, ux = Q1.y, uy = Q1.z, uz = Q1.w; \
          qx.y = w * ex + uy * ez - uz * ey; \
          qy.y = w * ey + uz * ex - ux * ez; \
          qz.y = w * ez + ux * ey - uy * ex; \
          qw.y = -(ux * ex + uy * ey + uz * ez); \
          p += kx.y * qx.y + ky.y * qy.y + kz.y * qz.y; } \
        { float ex = HX.z, ey = HY.z, ez = HZ.z; \
          float w = Q2.x, ux = Q2.y, uy = Q2.z, uz = Q2.w; \
          qx.z = w * ex + uy * ez - uz * ey; \
          qy.z = w * ey + uz * ex - ux * ez; \
          qz.z = w * ez + ux * ey - uy * ex; \
          qw.z = -(ux * ex + uy * ey + uz * ez); \
          p += kx.z * qx.z + ky.z * qy.z + kz.z * qz.z; } \
        { float ex = HX.w, ey = HY.w, ez = HZ.w; \
          float w = Q3.x, ux = Q3.y, uy = Q3.z, uz = Q3.w; \
          qx.w = w * ex + uy * ez - uz * ey; \
          qy.w = w * ey + uz * ex - ux * ez; \
          qz.w = w * ez + ux * ey - uy * ex; \
          qw.w = -(ux * ex + uy * ey + uz * ez); \
          p += kx.w * qx.w + ky.w * qy.w + kz.w * qz.w; } \
        p += __shfl_xor(p, 1, 64); \
        p += __shfl_xor(p, 2, 64); \
        p += __shfl_xor(p, 4, 64); \
        p += __shfl_xor(p, 8, 64); \
        bool valid = ((K0) + sub < end); \
        float a  = valid ? (p * 0.0625f) : -1e30f; \
        float mn = fmaxf(m, a); \
        float c  = __expf(m - mn); \
        float pe = valid ? __expf(a - mn) : 0.0f; \
        dnm = dnm * c + pe; \
        ax.x = ax.x * c + pe * qx.x; ax.y = ax.y * c + pe * qx.y; \
        ax.z = ax.z * c + pe * qx.z; ax.w = ax.w * c + pe * qx.w; \
        ay.x = ay.x * c + pe * qy.x; ay.y = ay.y * c + pe * qy.y; \
        ay.z = ay.z * c + pe * qy.z; ay.w = ay.w * c + pe * qy.w; \
        az.x = az.x * c + pe * qz.x; az.y = az.y * c + pe * qz.y; \
        az.z = az.z * c + pe * qz.z; az.w = az.w * c + pe * qz.w; \
        aw.x = aw.x * c + pe * qw.x; aw.y = aw.y * c + pe * qw.y; \
        aw.z = aw.z * c + pe * qw.z; aw.w = aw.w * c + pe * qw.w; \
        m = mn; }

    for (int k0 = start; k0 < end; k0 += 8) {
        // iter k0: compute A; prefetch her for k0+8; gathers for k0+4 (B set)
        int2 herC = hr[min(k0 + 8 + sub, last)];
        const float4* hB = (const float4*)(ent + (size_t)herB.x * (3 * HID));
        float4 hxB = hB[j], hyB = hB[16 + j], hzB = hB[32 + j];
        const float4* qrB = quat + (size_t)herB.y * HID + 4 * j;
        float4 q0B = qrB[0], q1B = qrB[1], q2B = qrB[2], q3B = qrB[3];
        COMPUTE(hxA, hyA, hzA, q0A, q1A, q2A, q3A, k0)

        // iter k0+4: compute B; prefetch her for k0+12; gathers for k0+8 (A set)
        int2 herD = hr[min(k0 + 12 + sub, last)];
        const float4* hA2 = (const float4*)(ent + (size_t)herC.x * (3 * HID));
        hxA = hA2[j]; hyA = hA2[16 + j]; hzA = hA2[32 + j];
        const float4* qrA2 = quat + (size_t)herC.y * HID + 4 * j;
        q0A = qrA2[0]; q1A = qrA2[1]; q2A = qrA2[2]; q3A = qrA2[3];
        COMPUTE(hxB, hyB, hzB, q0B, q1B, q2B, q3B, k0 + 4)

        herB = herD;
    }
    #undef COMPUTE

    // ---- merge the 4 edge-slot states across subwarps ----
    float mo = fmaxf(m, __shfl_xor(m, 16, 64));
    mo = fmaxf(mo, __shfl_xor(mo, 32, 64));
    float c = __expf(m - mo);             // deg==0 slot: underflows to 0
    dnm *= c;
    ax.x *= c; ax.y *= c; ax.z *= c; ax.w *= c;
    ay.x *= c; ay.y *= c; ay.z *= c; ay.w *= c;
    az.x *= c; az.y *= c; az.z *= c; az.w *= c;
    aw.x *= c; aw.y *= c; aw.z *= c; aw.w *= c;

    #pragma unroll
    for (int mask = 16; mask <= 32; mask <<= 1) {
        dnm += __shfl_xor(dnm, mask, 64);
        ax.x += __shfl_xor(ax.x, mask, 64); ax.y += __shfl_xor(ax.y, mask, 64);
        ax.z += __shfl_xor(ax.z, mask, 64); ax.w += __shfl_xor(ax.w, mask, 64);
        ay.x += __shfl_xor(ay.x, mask, 64); ay.y += __shfl_xor(ay.y, mask, 64);
        ay.z += __shfl_xor(ay.z, mask, 64); ay.w += __shfl_xor(ay.w, mask, 64);
        az.x += __shfl_xor(az.x, mask, 64); az.y += __shfl_xor(az.y, mask, 64);
        az.z += __shfl_xor(az.z, mask, 64); az.w += __shfl_xor(az.w, mask, 64);
        aw.x += __shfl_xor(aw.x, mask, 64); aw.y += __shfl_xor(aw.y, mask, 64);
        aw.z += __shfl_xor(aw.z, mask, 64); aw.w += __shfl_xor(aw.w, mask, 64);
    }

    float inv = (dnm > 0.0f) ? 1.0f / dnm : 0.0f;
    float4 lo = (sub & 1) ? ay : ax;
    float4 hi = (sub & 1) ? aw : az;
    float4 val = (sub & 2) ? hi : lo;
    val.x *= inv; val.y *= inv; val.z *= inv; val.w *= inv;
    o4[lane] = val;
}

extern "C" void kernel_launch(void* const* d_in, const int* in_sizes, int n_in,
                              void* d_out, int out_size, void* d_ws, size_t ws_size,
                              hipStream_t stream) {
    const float* ent  = (const float*)d_in[0];
    const float* rel  = (const float*)d_in[1];
    const int*   eidx = (const int*)d_in[2];
    float* out = (float*)d_out;

    const int n_ent = in_sizes[0] / (3 * HID);
    const int n_rel = in_sizes[1] / (4 * HID);
    const int E     = in_sizes[2] / 3;

    // Workspace layout
    int2* hr     = (int2*)d_ws;                     // E int2
    int*  hist   = (int*)(hr + E);                  // n_ent
    int*  base   = hist + n_ent;                    // n_ent + 1
    int*  base2  = base + n_ent + 1;                // n_ent
    int*  partial= base2 + n_ent;                   // <=256
    uintptr_t p = (uintptr_t)(partial + 256);
    p = (p + 15) & ~(uintptr_t)15;
    float4* quat = (float4*)p;                      // n_rel * HID

    hipMemsetAsync(hist, 0, (size_t)n_ent * sizeof(int), stream);

    const int qblocks  = (n_rel * HID + 255) / 256;
    const int eblocks1 = (E + 255) / 256;
    prep<<<qblocks + eblocks1, 256, 0, stream>>>(rel, quat, n_rel, eidx, E, hist, qblocks);

    const int nb = (n_ent + 255) / 256;             // 196 for n_ent=50000 (<=256)
    scan1<<<nb, 256, 0, stream>>>(hist, base, partial, n_ent);
    scan23<<<(n_ent + 1 + 255) / 256, 256, 0, stream>>>(base, base2, partial, nb, n_ent, E);

    scatter_hr<<<eblocks1, 256, 0, stream>>>(eidx, E, base2, hr);

    const int waves_per_block = 4;                  // 256 threads
    const int tblocks = (n_ent + waves_per_block - 1) / waves_per_block;
    seg_reduce<<<tblocks, 256, 0, stream>>>(ent, quat, hr, base, n_ent, out);
}